// Round 1
// baseline (8174.345 us; speedup 1.0000x reference)
//
#include <hip/hip_runtime.h>

#define NN 100000      // nodes
#define EE 3200000     // edges
#define INC 128        // in channels
#define HC 16          // hidden channels
#define BN_EPS 1e-5f

// ---------------- degree / normalization ----------------

__global__ void count_deg(const int* __restrict__ dst, float* __restrict__ deg) {
    int e = blockIdx.x * blockDim.x + threadIdx.x;
    if (e < EE) atomicAdd(&deg[dst[e]], 1.0f);
}

__global__ void compute_dis(const float* __restrict__ deg, float* __restrict__ dis) {
    int n = blockIdx.x * blockDim.x + threadIdx.x;
    if (n < NN) dis[n] = rsqrtf(deg[n] + 1.0f);   // deg includes +1 self loop
}

// ---------------- dense transforms ----------------

// x[N,128] @ W1[128,16] -> hw[N,16]. 256 thr = 16 nodes x 16 ch per block.
__global__ void gemm_x_w1(const float* __restrict__ x, const float* __restrict__ W1,
                          float* __restrict__ hw) {
    __shared__ float Ws[INC * HC];   // 8 KB
    int tid = threadIdx.x;
    for (int i = tid; i < INC * HC; i += 256) Ws[i] = W1[i];
    __syncthreads();
    int c = tid & 15;
    int node = blockIdx.x * 16 + (tid >> 4);
    if (node >= NN) return;
    const float4* xr = (const float4*)(x + (size_t)node * INC);
    float sum = 0.f;
#pragma unroll
    for (int k4 = 0; k4 < 32; ++k4) {
        float4 v = xr[k4];
        int k = k4 * 4;
        sum += v.x * Ws[k * 16 + c] + v.y * Ws[(k + 1) * 16 + c]
             + v.z * Ws[(k + 2) * 16 + c] + v.w * Ws[(k + 3) * 16 + c];
    }
    hw[node * HC + c] = sum;
}

// h[N,16] @ W[16,16] -> hw[N,16]
__global__ void gemm_h_w(const float* __restrict__ h, const float* __restrict__ W,
                         float* __restrict__ hw) {
    __shared__ float Ws[HC * HC];
    int tid = threadIdx.x;
    if (tid < HC * HC) Ws[tid] = W[tid];
    __syncthreads();
    int i = blockIdx.x * 256 + tid;
    if (i >= NN * HC) return;
    int n = i >> 4, c = i & 15;
    const float4* hr = (const float4*)(h + n * HC);
    float sum = 0.f;
#pragma unroll
    for (int q = 0; q < 4; ++q) {
        float4 v = hr[q];
        int k = q * 4;
        sum += v.x * Ws[k * 16 + c] + v.y * Ws[(k + 1) * 16 + c]
             + v.z * Ws[(k + 2) * 16 + c] + v.w * Ws[(k + 3) * 16 + c];
    }
    hw[i] = sum;
}

// ---------------- graph aggregation ----------------

// agg[n,c] = dis[n]^2 * hw[n,c] + b[c]   (self-loop + bias)
__global__ void init_agg(const float* __restrict__ hw, const float* __restrict__ dis,
                         const float* __restrict__ b, float* __restrict__ agg) {
    int i = blockIdx.x * blockDim.x + threadIdx.x;
    if (i >= NN * HC) return;
    int n = i >> 4, c = i & 15;
    float d = dis[n];
    agg[i] = d * d * hw[i] + b[c];
}

// one thread per edge: agg[dst] += dis[src]*dis[dst] * hw[src]
__global__ void scatter_edges(const int* __restrict__ src, const int* __restrict__ dst,
                              const float* __restrict__ dis, const float* __restrict__ hw,
                              float* __restrict__ agg) {
    int e = blockIdx.x * blockDim.x + threadIdx.x;
    if (e >= EE) return;
    int s = src[e], d = dst[e];
    float w = dis[s] * dis[d];
    const float4* hr = (const float4*)(hw + s * HC);
    float* ar = agg + d * HC;
#pragma unroll
    for (int q = 0; q < 4; ++q) {
        float4 v = hr[q];
        atomicAdd(&ar[q * 4 + 0], w * v.x);
        atomicAdd(&ar[q * 4 + 1], w * v.y);
        atomicAdd(&ar[q * 4 + 2], w * v.z);
        atomicAdd(&ar[q * 4 + 3], w * v.w);
    }
}

// ---------------- batch norm ----------------

// stats[0..15] = sum(relu(agg)), stats[16..31] = sumsq(relu(agg)) per channel
__global__ void bn_stats(const float* __restrict__ agg, float* __restrict__ stats) {
    int tid = threadIdx.x;
    float s = 0.f, ss = 0.f;
    for (int i = blockIdx.x * 256 + tid; i < NN * HC; i += gridDim.x * 256) {
        float v = agg[i];
        v = v > 0.f ? v : 0.f;
        s += v; ss += v * v;
    }
    __shared__ float sh[512];
    sh[tid] = s; sh[tid + 256] = ss;
    __syncthreads();
    for (int off = 128; off >= 16; off >>= 1) {
        if (tid < off) { sh[tid] += sh[tid + off]; sh[tid + 256] += sh[tid + 256 + off]; }
        __syncthreads();
    }
    if (tid < 16) {
        atomicAdd(&stats[tid], sh[tid]);
        atomicAdd(&stats[16 + tid], sh[tid + 256]);
    }
}

// h = (relu(agg) - mu) * rsqrt(var+eps) * gamma + beta
__global__ void bn_norm(const float* __restrict__ agg, const float* __restrict__ stats,
                        const float* __restrict__ gamma, const float* __restrict__ beta,
                        float* __restrict__ h) {
    int i = blockIdx.x * blockDim.x + threadIdx.x;
    if (i >= NN * HC) return;
    int c = i & 15;
    const float invN = 1.0f / NN;
    float mu = stats[c] * invN;
    float var = stats[16 + c] * invN - mu * mu;
    float v = agg[i];
    v = v > 0.f ? v : 0.f;
    h[i] = (v - mu) * rsqrtf(var + BN_EPS) * gamma[c] + beta[c];
}

// ---------------- final FC + log_softmax ----------------

__global__ void final_fc(const float* __restrict__ agg, const float* __restrict__ Wfc,
                         const float* __restrict__ bfc, float* __restrict__ out) {
    int n = blockIdx.x * blockDim.x + threadIdx.x;
    if (n >= NN) return;
    const float4* ar = (const float4*)(agg + n * HC);
    float z0 = bfc[0], z1 = bfc[1];
#pragma unroll
    for (int q = 0; q < 4; ++q) {
        float4 v = ar[q];
        int k = q * 4;
        z0 += v.x * Wfc[(k + 0) * 2 + 0] + v.y * Wfc[(k + 1) * 2 + 0]
            + v.z * Wfc[(k + 2) * 2 + 0] + v.w * Wfc[(k + 3) * 2 + 0];
        z1 += v.x * Wfc[(k + 0) * 2 + 1] + v.y * Wfc[(k + 1) * 2 + 1]
            + v.z * Wfc[(k + 2) * 2 + 1] + v.w * Wfc[(k + 3) * 2 + 1];
    }
    float m = fmaxf(z0, z1);
    float lse = m + logf(expf(z0 - m) + expf(z1 - m));
    out[n * 2 + 0] = z0 - lse;
    out[n * 2 + 1] = z1 - lse;
}

// ---------------- launch ----------------

extern "C" void kernel_launch(void* const* d_in, const int* in_sizes, int n_in,
                              void* d_out, int out_size, void* d_ws, size_t ws_size,
                              hipStream_t stream) {
    const float* x    = (const float*)d_in[0];
    const int*   ei   = (const int*)d_in[1];
    const int*   src  = ei;
    const int*   dstp = ei + EE;
    const float* W1   = (const float*)d_in[2];
    const float* b1   = (const float*)d_in[3];
    const float* W2   = (const float*)d_in[4];
    const float* b2   = (const float*)d_in[5];
    const float* W3   = (const float*)d_in[6];
    const float* b3   = (const float*)d_in[7];
    const float* g1   = (const float*)d_in[8];
    const float* be1  = (const float*)d_in[9];
    const float* g2   = (const float*)d_in[10];
    const float* be2  = (const float*)d_in[11];
    const float* Wfc  = (const float*)d_in[12];
    const float* bfc  = (const float*)d_in[13];
    float* out = (float*)d_out;

    float* W   = (float*)d_ws;
    float* dis = W;                       // [N]
    float* hw  = W + NN;                  // [16N]  (also reused as deg[N] early)
    float* agg = W + NN + 16 * NN;        // [16N]
    float* h   = W + NN + 32 * NN;        // [16N]
    float* stats = W + NN + 48 * NN;      // [32]
    float* deg = hw;

    const int TB = 256;
    const int gE  = (EE + TB - 1) / TB;
    const int gN  = (NN + TB - 1) / TB;
    const int gNH = (NN * HC + TB - 1) / TB;
    const int gX  = (NN + 15) / 16;

    // degree + normalization
    hipMemsetAsync(deg, 0, NN * sizeof(float), stream);
    count_deg<<<gE, TB, 0, stream>>>(dstp, deg);
    compute_dis<<<gN, TB, 0, stream>>>(deg, dis);

    // ---- layer 1 ----
    gemm_x_w1<<<gX, TB, 0, stream>>>(x, W1, hw);
    init_agg<<<gNH, TB, 0, stream>>>(hw, dis, b1, agg);
    scatter_edges<<<gE, TB, 0, stream>>>(src, dstp, dis, hw, agg);
    hipMemsetAsync(stats, 0, 32 * sizeof(float), stream);
    bn_stats<<<1024, TB, 0, stream>>>(agg, stats);
    bn_norm<<<gNH, TB, 0, stream>>>(agg, stats, g1, be1, h);

    // ---- layer 2 ----
    gemm_h_w<<<gNH, TB, 0, stream>>>(h, W2, hw);
    init_agg<<<gNH, TB, 0, stream>>>(hw, dis, b2, agg);
    scatter_edges<<<gE, TB, 0, stream>>>(src, dstp, dis, hw, agg);
    hipMemsetAsync(stats, 0, 32 * sizeof(float), stream);
    bn_stats<<<1024, TB, 0, stream>>>(agg, stats);
    bn_norm<<<gNH, TB, 0, stream>>>(agg, stats, g2, be2, h);

    // ---- layer 3 ----
    gemm_h_w<<<gNH, TB, 0, stream>>>(h, W3, hw);
    init_agg<<<gNH, TB, 0, stream>>>(hw, dis, b3, agg);
    scatter_edges<<<gE, TB, 0, stream>>>(src, dstp, dis, hw, agg);

    // ---- FC + log_softmax ----
    final_fc<<<gN, TB, 0, stream>>>(agg, Wfc, bfc, out);
}

// Round 2
// 691.671 us; speedup vs baseline: 11.8183x; 11.8183x over previous
//
#include <hip/hip_runtime.h>

#define NN 100000      // nodes
#define EE 3200000     // edges
#define INC 128        // in channels
#define HC 16          // hidden channels
#define BN_EPS 1e-5f

#define SCAN_TILE 1024                     // elements per scan block (256 thr x 4)
#define NBLK ((NN + SCAN_TILE - 1) / SCAN_TILE)   // 98 <= 256

// ---------------- degree / normalization ----------------

__global__ void count_deg_i(const int* __restrict__ dst, int* __restrict__ degi) {
    int e = blockIdx.x * blockDim.x + threadIdx.x;
    if (e < EE) atomicAdd(&degi[dst[e]], 1);
}

__global__ void compute_dis(const int* __restrict__ degi, float* __restrict__ dis) {
    int n = blockIdx.x * blockDim.x + threadIdx.x;
    if (n < NN) dis[n] = rsqrtf((float)degi[n] + 1.0f);   // +1 self loop
}

// ---------------- exclusive prefix sum over degi -> rowstart ----------------

__global__ void scan1(const int* __restrict__ degi, int* __restrict__ rowstart,
                      int* __restrict__ blocksums) {
    __shared__ int sh[256];
    int b = blockIdx.x, tid = threadIdx.x;
    int base = b * SCAN_TILE + tid * 4;
    int v0 = 0, v1 = 0, v2 = 0, v3 = 0;
    if (base + 0 < NN) v0 = degi[base + 0];
    if (base + 1 < NN) v1 = degi[base + 1];
    if (base + 2 < NN) v2 = degi[base + 2];
    if (base + 3 < NN) v3 = degi[base + 3];
    int s = v0 + v1 + v2 + v3;
    sh[tid] = s;
    __syncthreads();
    for (int off = 1; off < 256; off <<= 1) {
        int t = (tid >= off) ? sh[tid - off] : 0;
        __syncthreads();
        sh[tid] += t;
        __syncthreads();
    }
    int run = sh[tid] - s;   // exclusive prefix within block
    if (base + 0 < NN) rowstart[base + 0] = run;          run += v0;
    if (base + 1 < NN) rowstart[base + 1] = run;          run += v1;
    if (base + 2 < NN) rowstart[base + 2] = run;          run += v2;
    if (base + 3 < NN) rowstart[base + 3] = run;
    if (tid == 255) blocksums[b] = sh[255];
}

__global__ void scan2(int* __restrict__ blocksums) {   // single block
    __shared__ int sh[256];
    int tid = threadIdx.x;
    int v = (tid < NBLK) ? blocksums[tid] : 0;
    sh[tid] = v;
    __syncthreads();
    for (int off = 1; off < 256; off <<= 1) {
        int t = (tid >= off) ? sh[tid - off] : 0;
        __syncthreads();
        sh[tid] += t;
        __syncthreads();
    }
    if (tid < NBLK) blocksums[tid] = sh[tid] - v;   // exclusive
}

__global__ void scan3(int* __restrict__ rowstart, const int* __restrict__ blocksums,
                      int* __restrict__ cursor) {
    int idx = blockIdx.x * blockDim.x + threadIdx.x;
    if (idx < NN) {
        int r = rowstart[idx] + blocksums[idx / SCAN_TILE];
        rowstart[idx] = r;
        cursor[idx] = r;
    }
    if (idx == 0) rowstart[NN] = EE;
}

// ---------------- CSR fill ----------------

__global__ void fill_csr(const int* __restrict__ src, const int* __restrict__ dst,
                         const float* __restrict__ dis, int* __restrict__ cursor,
                         uint2* __restrict__ csr) {
    int e = blockIdx.x * blockDim.x + threadIdx.x;
    if (e >= EE) return;
    int s = src[e], d = dst[e];
    int pos = atomicAdd(&cursor[d], 1);
    float w = dis[s] * dis[d];
    csr[pos] = make_uint2((unsigned)s, __float_as_uint(w));
}

// ---------------- dense transforms ----------------

// x[N,128] @ W1[128,16] -> hw[N,16]; 16 nodes/block, x tile staged in LDS
__global__ void gemm_x_w1(const float* __restrict__ x, const float* __restrict__ W1,
                          float* __restrict__ hw) {
    __shared__ float Ws[INC * HC];        // 8 KB
    __shared__ float xs[16 * INC];        // 8 KB
    int tid = threadIdx.x;
    for (int i = tid; i < INC * HC; i += 256) Ws[i] = W1[i];
    // cooperative coalesced load of 16 node rows (2048 floats = 512 float4)
    int node0 = blockIdx.x * 16;
    const float4* xsrc = (const float4*)(x + (size_t)node0 * INC);
    float4* xdst = (float4*)xs;
    int nvalid = min(16, NN - node0);
    int nf4 = nvalid * 32;                // float4 count
    for (int i = tid; i < nf4; i += 256) xdst[i] = xsrc[i];
    __syncthreads();
    int c = tid & 15;
    int nl = tid >> 4;
    int node = node0 + nl;
    if (node >= NN) return;
    const float* xr = xs + nl * INC;
    float sum = 0.f;
#pragma unroll
    for (int k = 0; k < INC; ++k) sum += xr[k] * Ws[k * 16 + c];
    hw[node * HC + c] = sum;
}

// hw = (BN(relu(agg)) ) @ W   — fused BN+ReLU+16x16 GEMM
__global__ void gemm_bn_h_w(const float* __restrict__ agg, const float* __restrict__ stats,
                            const float* __restrict__ gamma, const float* __restrict__ beta,
                            const float* __restrict__ W, float* __restrict__ hw) {
    __shared__ float Ws[HC * HC];
    __shared__ float sc[HC], sf[HC];
    int tid = threadIdx.x;
    if (tid < HC * HC) Ws[tid] = W[tid];
    if (tid < HC) {
        const float invN = 1.0f / NN;
        float mu = stats[tid] * invN;
        float var = stats[16 + tid] * invN - mu * mu;
        float rs = rsqrtf(var + BN_EPS);
        sc[tid] = gamma[tid] * rs;
        sf[tid] = beta[tid] - mu * gamma[tid] * rs;
    }
    __syncthreads();
    int i = blockIdx.x * 256 + tid;
    if (i >= NN * HC) return;
    int n = i >> 4, c = i & 15;
    const float4* ar = (const float4*)(agg + n * HC);
    float sum = 0.f;
#pragma unroll
    for (int q = 0; q < 4; ++q) {
        float4 v = ar[q];
        int k = q * 4;
        float h0 = fmaxf(v.x, 0.f) * sc[k + 0] + sf[k + 0];
        float h1 = fmaxf(v.y, 0.f) * sc[k + 1] + sf[k + 1];
        float h2 = fmaxf(v.z, 0.f) * sc[k + 2] + sf[k + 2];
        float h3 = fmaxf(v.w, 0.f) * sc[k + 3] + sf[k + 3];
        sum += h0 * Ws[(k + 0) * 16 + c] + h1 * Ws[(k + 1) * 16 + c]
             + h2 * Ws[(k + 2) * 16 + c] + h3 * Ws[(k + 3) * 16 + c];
    }
    hw[i] = sum;
}

// ---------------- graph gather (no atomics) ----------------
// one wave per node: lanes = (edge_slot 0..3, channel 0..15)

__global__ void gcn_gather(const int* __restrict__ rowstart, const uint2* __restrict__ csr,
                           const float* __restrict__ dis, const float* __restrict__ hw,
                           const float* __restrict__ b, float* __restrict__ agg) {
    int tid = threadIdx.x;
    int lane = tid & 63;
    int node = blockIdx.x * 4 + (tid >> 6);
    if (node >= NN) return;
    int c = lane & 15;
    int e4 = lane >> 4;
    int beg = rowstart[node], end = rowstart[node + 1];
    float acc = 0.f;
    for (int e = beg + e4; e < end; e += 4) {
        uint2 ed = csr[e];
        acc += __uint_as_float(ed.y) * hw[ed.x * HC + c];
    }
    acc += __shfl_xor(acc, 16);
    acc += __shfl_xor(acc, 32);
    if (e4 == 0) {
        float d = dis[node];
        agg[node * HC + c] = acc + d * d * hw[node * HC + c] + b[c];
    }
}

// ---------------- batch norm stats (ReLU applied) ----------------

__global__ void bn_stats(const float* __restrict__ agg, float* __restrict__ stats) {
    int tid = threadIdx.x;
    float s = 0.f, ss = 0.f;
    for (int i = blockIdx.x * 256 + tid; i < NN * HC; i += gridDim.x * 256) {
        float v = agg[i];
        v = v > 0.f ? v : 0.f;
        s += v; ss += v * v;
    }
    __shared__ float sh[512];
    sh[tid] = s; sh[tid + 256] = ss;
    __syncthreads();
    for (int off = 128; off >= 16; off >>= 1) {
        if (tid < off) { sh[tid] += sh[tid + off]; sh[tid + 256] += sh[tid + 256 + off]; }
        __syncthreads();
    }
    if (tid < 16) {
        atomicAdd(&stats[tid], sh[tid]);
        atomicAdd(&stats[16 + tid], sh[tid + 256]);
    }
}

// ---------------- final FC + log_softmax ----------------

__global__ void final_fc(const float* __restrict__ agg, const float* __restrict__ Wfc,
                         const float* __restrict__ bfc, float* __restrict__ out) {
    int n = blockIdx.x * blockDim.x + threadIdx.x;
    if (n >= NN) return;
    const float4* ar = (const float4*)(agg + n * HC);
    float z0 = bfc[0], z1 = bfc[1];
#pragma unroll
    for (int q = 0; q < 4; ++q) {
        float4 v = ar[q];
        int k = q * 4;
        z0 += v.x * Wfc[(k + 0) * 2 + 0] + v.y * Wfc[(k + 1) * 2 + 0]
            + v.z * Wfc[(k + 2) * 2 + 0] + v.w * Wfc[(k + 3) * 2 + 0];
        z1 += v.x * Wfc[(k + 0) * 2 + 1] + v.y * Wfc[(k + 1) * 2 + 1]
            + v.z * Wfc[(k + 2) * 2 + 1] + v.w * Wfc[(k + 3) * 2 + 1];
    }
    float m = fmaxf(z0, z1);
    float lse = m + logf(expf(z0 - m) + expf(z1 - m));
    out[n * 2 + 0] = z0 - lse;
    out[n * 2 + 1] = z1 - lse;
}

// ---------------- launch ----------------

extern "C" void kernel_launch(void* const* d_in, const int* in_sizes, int n_in,
                              void* d_out, int out_size, void* d_ws, size_t ws_size,
                              hipStream_t stream) {
    const float* x    = (const float*)d_in[0];
    const int*   ei   = (const int*)d_in[1];
    const int*   src  = ei;
    const int*   dstp = ei + EE;
    const float* W1   = (const float*)d_in[2];
    const float* b1   = (const float*)d_in[3];
    const float* W2   = (const float*)d_in[4];
    const float* b2   = (const float*)d_in[5];
    const float* W3   = (const float*)d_in[6];
    const float* b3   = (const float*)d_in[7];
    const float* g1   = (const float*)d_in[8];
    const float* be1  = (const float*)d_in[9];
    const float* g2   = (const float*)d_in[10];
    const float* be2  = (const float*)d_in[11];
    const float* Wfc  = (const float*)d_in[12];
    const float* bfc  = (const float*)d_in[13];
    float* out = (float*)d_out;

    // workspace layout (8-byte aligned front to back)
    char* p = (char*)d_ws;
    uint2* csr     = (uint2*)p;                 p += (size_t)EE * 8;        // 25.6 MB
    float* hw      = (float*)p;                 p += (size_t)NN * HC * 4;   // 6.4 MB
    float* agg     = (float*)p;                 p += (size_t)NN * HC * 4;   // 6.4 MB
    float* dis     = (float*)p;                 p += (size_t)NN * 4;
    int*   degi    = (int*)p;                   p += (size_t)NN * 4;        // reused as cursor
    int*   rowstart= (int*)p;                   p += (size_t)(NN + 1) * 4;
    int*   blocksums=(int*)p;                   p += 256 * 4;
    float* stats1  = (float*)p;                 p += 32 * 4;
    float* stats2  = (float*)p;                 p += 32 * 4;
    int*   cursor  = degi;

    const int TB = 256;
    const int gE  = (EE + TB - 1) / TB;
    const int gN  = (NN + TB - 1) / TB;
    const int gNH = (NN * HC + TB - 1) / TB;
    const int gX  = (NN + 15) / 16;
    const int gG  = (NN + 3) / 4;

    // ---- CSR build ----
    hipMemsetAsync(degi, 0, NN * sizeof(int), stream);
    hipMemsetAsync(stats1, 0, 64 * sizeof(float), stream);   // stats1+stats2
    count_deg_i<<<gE, TB, 0, stream>>>(dstp, degi);
    compute_dis<<<gN, TB, 0, stream>>>(degi, dis);
    scan1<<<NBLK, TB, 0, stream>>>(degi, rowstart, blocksums);
    scan2<<<1, TB, 0, stream>>>(blocksums);
    scan3<<<gN, TB, 0, stream>>>(rowstart, blocksums, cursor);
    fill_csr<<<gE, TB, 0, stream>>>(src, dstp, dis, cursor, csr);

    // ---- layer 1 ----
    gemm_x_w1<<<gX, TB, 0, stream>>>(x, W1, hw);
    gcn_gather<<<gG, TB, 0, stream>>>(rowstart, csr, dis, hw, b1, agg);
    bn_stats<<<1024, TB, 0, stream>>>(agg, stats1);

    // ---- layer 2 ----
    gemm_bn_h_w<<<gNH, TB, 0, stream>>>(agg, stats1, g1, be1, W2, hw);
    gcn_gather<<<gG, TB, 0, stream>>>(rowstart, csr, dis, hw, b2, agg);
    bn_stats<<<1024, TB, 0, stream>>>(agg, stats2);

    // ---- layer 3 ----
    gemm_bn_h_w<<<gNH, TB, 0, stream>>>(agg, stats2, g2, be2, W3, hw);
    gcn_gather<<<gG, TB, 0, stream>>>(rowstart, csr, dis, hw, b3, agg);

    // ---- FC + log_softmax ----
    final_fc<<<gN, TB, 0, stream>>>(agg, Wfc, bfc, out);
}